// Round 4
// baseline (368.298 us; speedup 1.0000x reference)
//
#include <hip/hip_runtime.h>
#include <hip/hip_bf16.h>
#include <cstdint>

// LSTMCell B=8192, IN=H=1024, fp32 in/out.
// R7: R5's 2-phase counted-vmcnt schedule + 32x32x16 MFMA (m119: 99.8% of
// dense peak vs 16x16's 87%) with wave-tile 64x128 (4wm x 2wn waves, 2m x 4n
// frags -> 4 gates lane-local via R3's verified perm p=(j>>5)*128+gate*32+(j&31)).
// + 2D-chunked XCD swizzle (8bx x 8by per XCD) + c[] register prefetch.

#define B_DIM 8192
#define H_DIM 1024
#define K2    2048   // IN + H
#define N4    4096   // 4 * H
#define BK    64
#define BM    256
#define BN    256
#define NT    (K2 / BK)   // 32 K-tiles (even; peel assumes it)

typedef __bf16 bf16x8 __attribute__((ext_vector_type(8)));
typedef float  f32x16 __attribute__((ext_vector_type(16)));

__device__ __forceinline__ void async_load16(const __bf16* g, __bf16* l) {
  __builtin_amdgcn_global_load_lds(
      (__attribute__((address_space(1))) void*)(g),
      (__attribute__((address_space(3))) void*)(l),
      16, 0, 0);
}

__device__ __forceinline__ float sigm(float x) {
  return 1.0f / (1.0f + __expf(-x));
}
__device__ __forceinline__ float tanh_fast(float x) {
  return 2.0f / (1.0f + __expf(-2.0f * x)) - 1.0f;
}

// ---------------- cast A = [x | h] -> bf16 [8192][2048] ----------------
__global__ void cast_a(const float* __restrict__ x, const float* __restrict__ h,
                       __bf16* __restrict__ A) {
  int row = blockIdx.x;
  int k = threadIdx.x << 3;  // 0..2040 step 8
  const float* src = (k < H_DIM) ? (x + (size_t)row * H_DIM + k)
                                 : (h + (size_t)row * H_DIM + (k - H_DIM));
  float4 v0 = *(const float4*)src;
  float4 v1 = *(const float4*)(src + 4);
  bf16x8 o;
  o[0] = (__bf16)v0.x; o[1] = (__bf16)v0.y; o[2] = (__bf16)v0.z; o[3] = (__bf16)v0.w;
  o[4] = (__bf16)v1.x; o[5] = (__bf16)v1.y; o[6] = (__bf16)v1.z; o[7] = (__bf16)v1.w;
  *(bf16x8*)&A[(size_t)row * K2 + k] = o;
}

// ------------- cast + transpose + permute weights -> Bt [4096][2048] -------------
// Bt row p = (j>>5)*128 + gate*32 + (j&31); Bt[p][k] = W_cat[k][gate-col j]
// grid: (K2/64, H/32, 4 gates), block 256   (R3-verified)
__global__ void cast_w(const float* __restrict__ Wii, const float* __restrict__ Wif,
                       const float* __restrict__ Wig, const float* __restrict__ Wio,
                       const float* __restrict__ Whi, const float* __restrict__ Whf,
                       const float* __restrict__ Whg, const float* __restrict__ Who,
                       __bf16* __restrict__ Bt) {
  __shared__ float tile[64][33];
  int k0 = blockIdx.x * 64;
  int j0 = blockIdx.y * 32;
  int gate = blockIdx.z;
  const float* Wi[4] = {Wii, Wif, Wig, Wio};
  const float* Wh[4] = {Whi, Whf, Whg, Who};
  const float* W = (k0 < H_DIM) ? Wi[gate] : Wh[gate];
  int kb = (k0 < H_DIM) ? k0 : (k0 - H_DIM);

  int col = threadIdx.x & 31;
  int rr  = threadIdx.x >> 5;  // 0..7
#pragma unroll
  for (int p = 0; p < 8; ++p)
    tile[p * 8 + rr][col] = W[(size_t)(kb + p * 8 + rr) * H_DIM + j0 + col];
  __syncthreads();

  int jj = threadIdx.x >> 3;   // 0..31
  int ko = threadIdx.x & 7;    // 0..7 (8 k's each)
  int j = j0 + jj;
  int p = ((j >> 5) << 7) + (gate << 5) + (j & 31);
  bf16x8 o;
#pragma unroll
  for (int t = 0; t < 8; ++t) o[t] = (__bf16)tile[ko * 8 + t][jj];
  *(bf16x8*)&Bt[(size_t)p * K2 + k0 + ko * 8] = o;
}

// ---------------- fused GEMM + LSTM gate epilogue ----------------
// grid: 512 blocks (32 M-tiles x 16 N-tiles), block 512 (8 waves, 4M x 2N)
// Per phase (2 per K-tile, k-half = 2 k-steps of 16):
//   12 ds_read_b128 | 4 global_load_lds | 16 MFMA 32x32x16 | vmcnt(8) | s_barrier

#define STAGE_A(D, KH, TT) do { \
    async_load16(gA0 + (size_t)(TT) * 64 + (KH) * 32, &As_s[D][KH][wave << 9]); \
    async_load16(gA1 + (size_t)(TT) * 64 + (KH) * 32, &As_s[D][KH][4096 + (wave << 9)]); \
  } while (0)
#define STAGE_B(D, KH, TT) do { \
    async_load16(gB0 + (size_t)(TT) * 64 + (KH) * 32, &Bs_s[D][KH][wave << 9]); \
    async_load16(gB1 + (size_t)(TT) * 64 + (KH) * 32, &Bs_s[D][KH][4096 + (wave << 9)]); \
  } while (0)
#define STAGE_AB(D, KH, TT) do { STAGE_A(D, KH, TT); STAGE_B(D, KH, TT); } while (0)

// frags: aF[tm][s], bF[tn][s]; s = k-step within half (k = s*16 + h8*8 ..+7)
#define DS_AB(DB, KK) do { \
    const __bf16* ap_ = &As_s[DB][KK][a_off]; \
    const __bf16* bp_ = &Bs_s[DB][KK][b_off]; \
    aF[0][0] = *(const bf16x8*)(ap_ + o0);        aF[0][1] = *(const bf16x8*)(ap_ + o1); \
    aF[1][0] = *(const bf16x8*)(ap_ + 1024 + o0); aF[1][1] = *(const bf16x8*)(ap_ + 1024 + o1); \
    bF[0][0] = *(const bf16x8*)(bp_ + o0);        bF[0][1] = *(const bf16x8*)(bp_ + o1); \
    bF[1][0] = *(const bf16x8*)(bp_ + 1024 + o0); bF[1][1] = *(const bf16x8*)(bp_ + 1024 + o1); \
    bF[2][0] = *(const bf16x8*)(bp_ + 2048 + o0); bF[2][1] = *(const bf16x8*)(bp_ + 2048 + o1); \
    bF[3][0] = *(const bf16x8*)(bp_ + 3072 + o0); bF[3][1] = *(const bf16x8*)(bp_ + 3072 + o1); \
  } while (0)

#define MFMA16() do { \
    __builtin_amdgcn_s_setprio(1); \
    _Pragma("unroll") \
    for (int tm = 0; tm < 2; ++tm) { \
      _Pragma("unroll") \
      for (int tn = 0; tn < 4; ++tn) { \
        acc[tm][tn] = __builtin_amdgcn_mfma_f32_32x32x16_bf16( \
            aF[tm][0], bF[tn][0], acc[tm][tn], 0, 0, 0); \
        acc[tm][tn] = __builtin_amdgcn_mfma_f32_32x32x16_bf16( \
            aF[tm][1], bF[tn][1], acc[tm][tn], 0, 0, 0); \
      } \
    } \
    __builtin_amdgcn_s_setprio(0); \
  } while (0)

#define GATE(N) asm volatile("s_waitcnt vmcnt(" #N ")" ::: "memory")

#define PHASE(DB, KK, STG, GT) do { \
    DS_AB(DB, KK); \
    STG; \
    MFMA16(); \
    GT; \
    __builtin_amdgcn_s_barrier(); \
  } while (0)

__global__ __launch_bounds__(512, 2) void lstm_gemm(
    const __bf16* __restrict__ A,    // [8192][2048]
    const __bf16* __restrict__ Bt,   // [4096][2048] permuted rows
    const float* __restrict__ c,
    const float* __restrict__ bi, const float* __restrict__ bf_,
    const float* __restrict__ bg, const float* __restrict__ bo,
    float* __restrict__ out_c, float* __restrict__ out_h) {
  // [buf][khalf][256 rows][32 cols] bf16; row = 64 B = 4 x 16B slots.
  // phys slot s of row r holds global k-segment s ^ ((r>>1)&3).
  __shared__ __align__(16) __bf16 As_s[2][2][256 * 32];   // 64 KB
  __shared__ __align__(16) __bf16 Bs_s[2][2][256 * 32];   // 64 KB

  // 2D-chunked XCD swizzle: XCD x owns an 8bx x 8by region (bijective, 512%8==0)
  const int wg  = blockIdx.x;
  const int xcd = wg & 7;
  const int ii  = wg >> 3;                        // 0..63 within XCD
  const int bx  = ((xcd & 3) << 3) + (ii & 7);    // 0..31
  const int by  = ((xcd >> 2) << 3) + (ii >> 3);  // 0..15
  const int m0  = bx << 8;
  const int n0  = by << 8;

  const int tid  = threadIdx.x;
  const int wave = tid >> 6;        // 0..7
  const int lane = tid & 63;
  const int wm   = wave >> 1;       // 0..3 : M quarter (64 rows)
  const int wn   = wave & 1;        // 0..1 : N half (128 perm-cols)
  const int lane31 = lane & 31;
  const int h8   = lane >> 5;       // k-seg within k-step

  // staging: wave w stages rows w*16+(lane>>2) of each 128-row half; lane
  // writes phys slot lane&3; pre-swizzled source seg = (lane&3)^((lane>>3)&3).
  const int srow = (wave << 4) + (lane >> 2);
  const int sgc  = (lane & 3) ^ ((lane >> 3) & 3);
  const __bf16* gA0 = A  + (size_t)(m0 + srow) * K2 + sgc * 8;
  const __bf16* gA1 = gA0 + (size_t)128 * K2;
  const __bf16* gB0 = Bt + (size_t)(n0 + srow) * K2 + sgc * 8;
  const __bf16* gB1 = gB0 + (size_t)128 * K2;

  // fragment read offsets: row = (frag base + lane31), seg = s*2 + h8,
  // phys slot = seg ^ ((row>>1)&3) = seg ^ ((lane31>>1)&3)  (bases mult of 32)
  const int swl = (lane31 >> 1) & 3;
  const int o0  = (h8 ^ swl) << 3;           // elems, k-step s=0
  const int o1  = ((2 + h8) ^ swl) << 3;     // elems, k-step s=1
  const int a_off = (((wm << 6) + lane31) << 5);
  const int b_off = (((wn << 7) + lane31) << 5);

  f32x16 acc[2][4] = {};
  bf16x8 aF[2][2], bF[4][2];

  // ---- prologue: A+B(0,0,0), A+B(0,1,0), A+B(1,0,1) = 12 loads/thread ----
  STAGE_AB(0, 0, 0);
  STAGE_AB(0, 1, 0);
  STAGE_AB(1, 0, 1);
  GATE(8);                          // tile0 kh0 landed
  __builtin_amdgcn_s_barrier();

  // ---- main loop, 2 tiles/iter (static buffer indices) ----
  for (int t = 0; t < NT - 2; t += 2) {
    PHASE(0, 0, STAGE_AB(1, 1, t + 1), GATE(8));   // tile t   kh0
    PHASE(0, 1, STAGE_AB(0, 0, t + 2), GATE(8));   // tile t   kh1
    PHASE(1, 0, STAGE_AB(0, 1, t + 2), GATE(8));   // tile t+1 kh0
    PHASE(1, 1, STAGE_AB(1, 0, t + 3), GATE(8));   // tile t+1 kh1
  }
  // ---- peel tiles NT-2 (buf0), NT-1 (buf1) ----
  PHASE(0, 0, STAGE_AB(1, 1, NT - 1), GATE(8));
  PHASE(0, 1, (void)0, GATE(4));
  PHASE(1, 0, (void)0, GATE(0));

  // ---- c[] prefetch into registers (hides under last tile's MFMA) ----
  // epilogue mapping (32x32 C/D, R3-verified): col j lane-local, gate == tn.
  const int jj = (by << 6) + (wn << 5) + lane31;   // j = (by*2+wn)*32 + lane31
  const int rb = m0 + (wm << 6) + (h8 << 2);
  float cpre[2][16];
#pragma unroll
  for (int tm = 0; tm < 2; ++tm)
#pragma unroll
    for (int r = 0; r < 16; ++r)
      cpre[tm][r] = c[(size_t)(rb + tm * 32 + (r & 3) + 8 * (r >> 2)) * H_DIM + jj];

  DS_AB(1, 1);
  MFMA16();

  // ---- fused epilogue ----
  const float vbi = bi[jj], vbf = bf_[jj], vbg = bg[jj], vbo = bo[jj];
#pragma unroll
  for (int tm = 0; tm < 2; ++tm) {
#pragma unroll
    for (int r = 0; r < 16; ++r) {
      const int row = rb + tm * 32 + (r & 3) + 8 * (r >> 2);
      const size_t idx = (size_t)row * H_DIM + jj;
      const float gi = sigm(acc[tm][0][r] + vbi);
      const float gf = sigm(acc[tm][1][r] + vbf);
      const float gg = tanh_fast(acc[tm][2][r] + vbg);
      const float go = sigm(acc[tm][3][r] + vbo);
      const float nc = gf * cpre[tm][r] + gi * gg;
      out_c[idx] = nc;
      out_h[idx] = go * tanh_fast(nc);
    }
  }
}

extern "C" void kernel_launch(void* const* d_in, const int* in_sizes, int n_in,
                              void* d_out, int out_size, void* d_ws, size_t ws_size,
                              hipStream_t stream) {
  const float* x   = (const float*)d_in[0];
  const float* c   = (const float*)d_in[1];
  const float* h   = (const float*)d_in[2];
  const float* Wii = (const float*)d_in[3];
  const float* Wif = (const float*)d_in[4];
  const float* Wig = (const float*)d_in[5];
  const float* Wio = (const float*)d_in[6];
  const float* Whi = (const float*)d_in[7];
  const float* Whf = (const float*)d_in[8];
  const float* Whg = (const float*)d_in[9];
  const float* Who = (const float*)d_in[10];
  const float* bi  = (const float*)d_in[11];
  const float* bf_ = (const float*)d_in[12];
  const float* bg  = (const float*)d_in[13];
  const float* bo  = (const float*)d_in[14];

  __bf16* Abf = (__bf16*)d_ws;                                   // 32 MiB
  __bf16* Bt  = (__bf16*)((char*)d_ws + (size_t)B_DIM * K2 * 2); // 16 MiB

  float* out_c = (float*)d_out;
  float* out_h = out_c + (size_t)B_DIM * H_DIM;

  cast_a<<<B_DIM, 256, 0, stream>>>(x, h, Abf);
  dim3 gw(K2 / 64, H_DIM / 32, 4);
  cast_w<<<gw, 256, 0, stream>>>(Wii, Wif, Wig, Wio, Whi, Whf, Whg, Who, Bt);
  lstm_gemm<<<dim3((B_DIM / BM) * (N4 / BN)), 512, 0, stream>>>(
      Abf, Bt, c, bi, bf_, bg, bo, out_c, out_h);
}

// Round 5
// 349.108 us; speedup vs baseline: 1.0550x; 1.0550x over previous
//
#include <hip/hip_runtime.h>
#include <hip/hip_bf16.h>
#include <cstdint>

// LSTMCell B=8192, IN=H=1024, fp32 in/out.
// R8: B-from-L2 restructure. Weights (16 MB, L2-resident) are read per-wave
// as fragment-native coalesced global loads (reg ping-pong, 1 phase ahead);
// LDS stages ONLY A (4 x 8KB units) -> 32 KB/block -> 3 blocks/CU, so
// barrier stalls of one block hide under another block's MFMA.
// Tile 128x128, 4 waves (2m x 2n), wave-tile 64x64, 16x16x32 MFMA
// (R5's verified conflict-free 16-row LDS pattern + XOR swizzle).

#define B_DIM 8192
#define H_DIM 1024
#define K2    2048   // IN + H
#define N4    4096   // 4 * H
#define BM    128
#define BN    128
#define NPH   64     // phases = K2/32 kblks

typedef __bf16 bf16x8 __attribute__((ext_vector_type(8)));
typedef float  f32x4  __attribute__((ext_vector_type(4)));

__device__ __forceinline__ void async_load16(const __bf16* g, __bf16* l) {
  __builtin_amdgcn_global_load_lds(
      (__attribute__((address_space(1))) void*)(g),
      (__attribute__((address_space(3))) void*)(l),
      16, 0, 0);
}

__device__ __forceinline__ float sigm(float x) {
  return 1.0f / (1.0f + __expf(-x));
}
__device__ __forceinline__ float tanh_fast(float x) {
  return 2.0f / (1.0f + __expf(-2.0f * x)) - 1.0f;
}

// ---------------- cast A = [x | h] -> bf16 [8192][2048] ----------------
__global__ void cast_a(const float* __restrict__ x, const float* __restrict__ h,
                       __bf16* __restrict__ A) {
  int row = blockIdx.x;
  int k = threadIdx.x << 3;  // 0..2040 step 8
  const float* src = (k < H_DIM) ? (x + (size_t)row * H_DIM + k)
                                 : (h + (size_t)row * H_DIM + (k - H_DIM));
  float4 v0 = *(const float4*)src;
  float4 v1 = *(const float4*)(src + 4);
  bf16x8 o;
  o[0] = (__bf16)v0.x; o[1] = (__bf16)v0.y; o[2] = (__bf16)v0.z; o[3] = (__bf16)v0.w;
  o[4] = (__bf16)v1.x; o[5] = (__bf16)v1.y; o[6] = (__bf16)v1.z; o[7] = (__bf16)v1.w;
  *(bf16x8*)&A[(size_t)row * K2 + k] = o;
}

// ---- cast + transpose weights -> fragment-native Bt ----
// Logical perm-row p = (j>>4)*64 + gate*16 + (j&15); frag F = p>>4 =
// (j>>4)*4 + gate. Storage: chunk (F, kblk) holds 64 lanes x 16B:
// elem[(F*64+kblk)*512 + (seg*16 + (j&15))*8 + e] = W_cat[kblk*32+seg*8+e][gate-col j]
// grid: (K2/64, H/32, 4 gates), block 256
__global__ void cast_w(const float* __restrict__ Wii, const float* __restrict__ Wif,
                       const float* __restrict__ Wig, const float* __restrict__ Wio,
                       const float* __restrict__ Whi, const float* __restrict__ Whf,
                       const float* __restrict__ Whg, const float* __restrict__ Who,
                       __bf16* __restrict__ Bt) {
  __shared__ float tile[64][33];
  int k0 = blockIdx.x * 64;
  int j0 = blockIdx.y * 32;
  int gate = blockIdx.z;
  const float* Wi[4] = {Wii, Wif, Wig, Wio};
  const float* Wh[4] = {Whi, Whf, Whg, Who};
  const float* W = (k0 < H_DIM) ? Wi[gate] : Wh[gate];
  int kb = (k0 < H_DIM) ? k0 : (k0 - H_DIM);

  int col = threadIdx.x & 31;
  int rr  = threadIdx.x >> 5;  // 0..7
#pragma unroll
  for (int p = 0; p < 8; ++p)
    tile[p * 8 + rr][col] = W[(size_t)(kb + p * 8 + rr) * H_DIM + j0 + col];
  __syncthreads();

  const int jrow = threadIdx.x & 15;         // j & 15
  const int seg  = (threadIdx.x >> 4) & 3;   // k-seg of 8 within kblk
  const int kbl  = (threadIdx.x >> 6) & 1;   // kblk within this 64-k tile
  const int jh   = threadIdx.x >> 7;         // j half (0/1)
  const int j    = j0 + jh * 16 + jrow;
  const int F    = ((j >> 4) << 2) + gate;
  const int kblk = (k0 >> 5) + kbl;
  bf16x8 o;
#pragma unroll
  for (int e = 0; e < 8; ++e) o[e] = (__bf16)tile[kbl * 32 + seg * 8 + e][jh * 16 + jrow];
  *(bf16x8*)&Bt[((size_t)F * 64 + kblk) * 512 + (seg * 16 + jrow) * 8] = o;
}

// ---------------- fused GEMM + LSTM gate epilogue ----------------
// grid: 2048 blocks (64 M-tiles x 32 N-tiles), block 256 (4 waves, 2M x 2N)
// Phase p (kblk p): { 4 ds_read A | 4 global B-frag loads (p+1) | 16 MFMA |
//                     stage A unit (p+3) | vmcnt(6) | s_barrier }

#define BLOAD(DST, P1) do { \
    DST[0] = *(const bf16x8*)(gB + (size_t)(P1) * 512); \
    DST[1] = *(const bf16x8*)(gB + 32768 + (size_t)(P1) * 512); \
    DST[2] = *(const bf16x8*)(gB + 65536 + (size_t)(P1) * 512); \
    DST[3] = *(const bf16x8*)(gB + 98304 + (size_t)(P1) * 512); \
  } while (0)

#define ASTAGE(U, KB) do { \
    async_load16(gA0 + (size_t)(KB) * 32, &As_s[U][wave << 9]); \
    async_load16(gA1 + (size_t)(KB) * 32, &As_s[U][2048 + (wave << 9)]); \
  } while (0)

#define AREAD(U) do { \
    const __bf16* ap_ = &As_s[U][a_off]; \
    aF[0] = *(const bf16x8*)(ap_); \
    aF[1] = *(const bf16x8*)(ap_ + 512); \
    aF[2] = *(const bf16x8*)(ap_ + 1024); \
    aF[3] = *(const bf16x8*)(ap_ + 1536); \
  } while (0)

#define MFMA16(BF) do { \
    __builtin_amdgcn_s_setprio(1); \
    _Pragma("unroll") \
    for (int mi = 0; mi < 4; ++mi) { \
      _Pragma("unroll") \
      for (int tn = 0; tn < 4; ++tn) \
        acc[mi][tn] = __builtin_amdgcn_mfma_f32_16x16x32_bf16( \
            aF[mi], BF[tn], acc[mi][tn], 0, 0, 0); \
    } \
    __builtin_amdgcn_s_setprio(0); \
  } while (0)

#define GATE(N) asm volatile("s_waitcnt vmcnt(" #N ")" ::: "memory")
#define BAR()   __builtin_amdgcn_s_barrier()

// order: AREAD | BLOAD(next) | MFMA | ASTAGE  -> the compiler's automatic
// bF-wait (vmcnt<=6) leaves each A-stage 2 full phases of slack.
#define PH(I, UST, BFU, BFL, P) do { \
    AREAD(I); \
    BLOAD(BFL, (P) + 1); \
    MFMA16(BFU); \
    ASTAGE(UST, (P) + 3); \
    GATE(6); \
    BAR(); \
  } while (0)

__global__ __launch_bounds__(256, 3) void lstm_gemm(
    const __bf16* __restrict__ A,    // [8192][2048]
    const __bf16* __restrict__ Bt,   // fragment-native [256 frags][64 kblk][512]
    const float* __restrict__ c,
    const float* __restrict__ bi, const float* __restrict__ bf_,
    const float* __restrict__ bg, const float* __restrict__ bo,
    float* __restrict__ out_c, float* __restrict__ out_h) {
  // A units: [4][128 rows][32 cols] bf16; row = 64 B = 4 x 16B slots.
  // phys slot s of row r holds global k-segment s ^ ((r>>1)&3).
  __shared__ __align__(16) __bf16 As_s[4][128 * 32];   // 32 KB

  // XCD swizzle: XCD x owns bx-band [8x, 8x+8) x all by (bijective, 2048%8==0)
  const int wg  = blockIdx.x;
  const int xcd = wg & 7;
  const int ii  = wg >> 3;                  // 0..255
  const int bx  = (xcd << 3) + (ii & 7);    // 0..63
  const int by  = ii >> 3;                  // 0..31
  const int m0  = bx << 7;

  const int tid  = threadIdx.x;
  const int wave = tid >> 6;        // 0..3
  const int lane = tid & 63;
  const int wm   = wave >> 1;       // 0..1 : M half (64 rows)
  const int wn   = wave & 1;        // 0..1 : N half (4 frags = 64 perm-cols)

  // A staging: thread stages row tid>>2 (and +64), phys slot tid&3,
  // pre-swizzled source segment (tid&3) ^ ((row>>1)&3) = (tid&3)^((tid>>3)&3).
  const int srow = tid >> 2;
  const int sgc  = (tid & 3) ^ ((tid >> 3) & 3);
  const __bf16* gA0 = A + (size_t)(m0 + srow) * K2 + sgc * 8;
  const __bf16* gA1 = gA0 + (size_t)64 * K2;

  // B fragment base: frag F = by*8 + wn*4 + tn; chunk elem = (F*64+kblk)*512 + lane*8
  const __bf16* gB = Bt + (size_t)(by * 8 + wn * 4) * 32768 + lane * 8;

  // A fragment read: row=(lane&15), phys slot=(lane>>4)^((lane>>1)&3)
  const int a_off = (wm << 11) + ((lane & 15) << 5) +
                    (((lane >> 4) ^ ((lane >> 1) & 3)) << 3);

  f32x4 acc[4][4] = {};
  bf16x8 aF[4], bfa[4], bfb[4];

  // ---- prologue: stage units 0,1,2 (kblk 0,1,2); load B kblk 0 ----
  ASTAGE(0, 0); ASTAGE(1, 1); ASTAGE(2, 2);
  BLOAD(bfa, 0);
  GATE(8);                          // unit 0 landed (10 outstanding -> 8)
  BAR();

  // ---- main loop: phases 0..59, 4 per iter (static unit indices) ----
  for (int p0 = 0; p0 < 60; p0 += 4) {
    PH(0, 3, bfa, bfb, p0 + 0);   // read u0, stage u3=(p+3)&3
    PH(1, 0, bfb, bfa, p0 + 1);
    PH(2, 1, bfa, bfb, p0 + 2);
    PH(3, 2, bfb, bfa, p0 + 3);
  }
  // ---- peel phases 60..63 ----
  AREAD(0); BLOAD(bfb, 61); MFMA16(bfa); ASTAGE(3, 63); GATE(6); BAR();  // p60
  AREAD(1); BLOAD(bfa, 62); MFMA16(bfb); GATE(4); BAR();                 // p61
  AREAD(2); BLOAD(bfb, 63); MFMA16(bfa); GATE(0); BAR();                 // p62
  AREAD(3); MFMA16(bfb);                                                 // p63

  // ---- fused epilogue: gate == tn, lane-local ----
  // j = by*32 + wn*16 + (lane&15); C/D row = base + (lane>>4)*4 + r
  const int jj = (by << 5) + (wn << 4) + (lane & 15);
  const float vbi = bi[jj], vbf = bf_[jj], vbg = bg[jj], vbo = bo[jj];
  const int rb = m0 + (wm << 6) + ((lane >> 4) << 2);
#pragma unroll
  for (int mi = 0; mi < 4; ++mi) {
#pragma unroll
    for (int r = 0; r < 4; ++r) {
      const int row = rb + mi * 16 + r;
      const size_t idx = (size_t)row * H_DIM + jj;
      const float gi = sigm(acc[mi][0][r] + vbi);
      const float gf = sigm(acc[mi][1][r] + vbf);
      const float gg = tanh_fast(acc[mi][2][r] + vbg);
      const float go = sigm(acc[mi][3][r] + vbo);
      const float cv = c[idx];
      const float nc = gf * cv + gi * gg;
      out_c[idx] = nc;
      out_h[idx] = go * tanh_fast(nc);
    }
  }
}

extern "C" void kernel_launch(void* const* d_in, const int* in_sizes, int n_in,
                              void* d_out, int out_size, void* d_ws, size_t ws_size,
                              hipStream_t stream) {
  const float* x   = (const float*)d_in[0];
  const float* c   = (const float*)d_in[1];
  const float* h   = (const float*)d_in[2];
  const float* Wii = (const float*)d_in[3];
  const float* Wif = (const float*)d_in[4];
  const float* Wig = (const float*)d_in[5];
  const float* Wio = (const float*)d_in[6];
  const float* Whi = (const float*)d_in[7];
  const float* Whf = (const float*)d_in[8];
  const float* Whg = (const float*)d_in[9];
  const float* Who = (const float*)d_in[10];
  const float* bi  = (const float*)d_in[11];
  const float* bf_ = (const float*)d_in[12];
  const float* bg  = (const float*)d_in[13];
  const float* bo  = (const float*)d_in[14];

  __bf16* Abf = (__bf16*)d_ws;                                   // 32 MiB
  __bf16* Bt  = (__bf16*)((char*)d_ws + (size_t)B_DIM * K2 * 2); // 16 MiB

  float* out_c = (float*)d_out;
  float* out_h = out_c + (size_t)B_DIM * H_DIM;

  cast_a<<<B_DIM, 256, 0, stream>>>(x, h, Abf);
  dim3 gw(K2 / 64, H_DIM / 32, 4);
  cast_w<<<gw, 256, 0, stream>>>(Wii, Wif, Wig, Wio, Whi, Whf, Whg, Who, Bt);
  lstm_gemm<<<dim3((B_DIM / BM) * (N4 / BN)), 256, 0, stream>>>(
      Abf, Bt, c, bi, bf_, bg, bo, out_c, out_h);
}